// Round 1
// 567.755 us; speedup vs baseline: 1.6274x; 1.6274x over previous
//
#include <hip/hip_runtime.h>

#define SEQ 131072
#define DIM 256
#define DTC 0.1f
#define EPSC 1e-8f

typedef __attribute__((ext_vector_type(8))) short bf16x8;
typedef __attribute__((ext_vector_type(4))) float f32x4;
typedef __attribute__((ext_vector_type(4))) int   i32x4;

// f32 -> bf16 round-to-nearest-even (no NaN handling needed: data is bounded)
static __device__ __forceinline__ unsigned short f2bf(float f){
  unsigned int u = __builtin_bit_cast(unsigned int, f);
  u += 0x7fffu + ((u >> 16) & 1u);
  return (unsigned short)(u >> 16);
}

// ---------------------------------------------------------------------------
// Stage 0: M1 = I + cH  (c = -i*dt/hbar), and P = I.   65536 threads.
//   cH = -i*s*(Hr + i*Hi) = s*Hi - i*s*Hr   with s = dt/hbar.
// ---------------------------------------------------------------------------
__global__ __launch_bounds__(256)
void k_init(const float* __restrict__ hr, const float* __restrict__ hi,
            const float* __restrict__ hbar,
            float* __restrict__ m1r, float* __restrict__ m1i,
            float* __restrict__ pr,  float* __restrict__ pi)
{
  const int idx = blockIdx.x * 256 + threadIdx.x;   // grid 256 -> 65536
  const int r = idx >> 8, c = idx & 255;
  const float s = DTC / hbar[0];
  const float diag = (r == c) ? 1.0f : 0.0f;
  m1r[idx] = diag + s * hi[idx];
  m1i[idx] =       -s * hr[idx];
  pr [idx] = diag;
  pi [idx] = 0.0f;
}

// ---------------------------------------------------------------------------
// One square-and-multiply stage:  out = (in*in) * (bit(T,BIT) ? M1 : I)
// Block r computes output row r. Both matmuls fused via LDS row buffer.
// All f32 — the matrix power is exact to f32 precision.
// ---------------------------------------------------------------------------
template<int BIT>
__global__ __launch_bounds__(256)
void k_step(const float* __restrict__ inr, const float* __restrict__ ini,
            const float* __restrict__ m1r, const float* __restrict__ m1i,
            const int* __restrict__ ts,
            float* __restrict__ outr, float* __restrict__ outi)
{
  __shared__ float rr[256], ri[256], sr[256], si[256];
  const int r = blockIdx.x, c = threadIdx.x;
  rr[c] = inr[r*256 + c];
  ri[c] = ini[r*256 + c];
  __syncthreads();

  float ar = 0.f, ai = 0.f;
  for (int k = 0; k < 256; ++k){
    const float br = inr[k*256 + c], bi = ini[k*256 + c];  // coalesced across c
    const float xr = rr[k],          xi = ri[k];           // LDS broadcast
    ar = fmaf(xr, br, fmaf(-xi, bi, ar));
    ai = fmaf(xr, bi, fmaf( xi, br, ai));
  }

  const bool bit = ((ts[0] >> BIT) & 1) != 0;   // block-uniform branch
  if (!bit){
    outr[r*256 + c] = ar; outi[r*256 + c] = ai;
    return;
  }
  sr[c] = ar; si[c] = ai;
  __syncthreads();
  float orr = 0.f, oii = 0.f;
  for (int k = 0; k < 256; ++k){
    const float br = m1r[k*256 + c], bi = m1i[k*256 + c];
    const float xr = sr[k],          xi = si[k];
    orr = fmaf(xr, br, fmaf(-xi, bi, orr));
    oii = fmaf(xr, bi, fmaf( xi, br, oii));
  }
  outr[r*256 + c] = orr; outi[r*256 + c] = oii;
}

// ---------------------------------------------------------------------------
// Main apply:  out = normalize_rows( q0 + q0 @ R^T ),  R = M^T_power - I.
// Identity split keeps q0 exact in f32; only R (O(0.1) entries) goes bf16.
// Structure identical to the verified per-step kernel, but ONE pass.
// ---------------------------------------------------------------------------
template<int STORE_COMPLEX>
__global__ __launch_bounds__(512, 2)
void apply_kernel(const float* __restrict__ psi_re, const float* __restrict__ psi_im,
                  const float* __restrict__ Pre,    const float* __restrict__ Pim,
                  const int* __restrict__ tsteps,   float* __restrict__ out)
{
  // pitch 272 ushorts (544 B/row): same bank-spread as the verified kernel
  __shared__ alignas(16) unsigned short a_re[64][272];
  __shared__ alignas(16) unsigned short a_im[64][272];
  __shared__ float partials[64][8];
  __shared__ float scales[64];

  const int tid  = threadIdx.x;
  const int wv   = tid >> 6;
  const int lane = tid & 63;
  const int lq   = lane >> 4;   // 16-lane group
  const int lr   = lane & 15;
  const int brow = blockIdx.x << 6;
  const int cbase = wv << 5;    // wave's first column
  const int T = tsteps[0];

  // ---- B fragments: B[k][c] = R[c][k] = P[c][k] - delta(c,k), bf16 ----
  // B-frag layout: col = lane&15, k = (lane>>4)*8 + i (8 consecutive k's).
  bf16x8 bhr[2][8], bhi[2][8];
  #pragma unroll
  for (int ct = 0; ct < 2; ++ct){
    const int c = cbase + ct*16 + lr;
    #pragma unroll
    for (int kt = 0; kt < 8; ++kt){
      const int kb = kt*32 + lq*8;
      const float4 pr0 = *reinterpret_cast<const float4*>(&Pre[c*DIM + kb]);
      const float4 pr1 = *reinterpret_cast<const float4*>(&Pre[c*DIM + kb + 4]);
      const float4 pi0 = *reinterpret_cast<const float4*>(&Pim[c*DIM + kb]);
      const float4 pi1 = *reinterpret_cast<const float4*>(&Pim[c*DIM + kb + 4]);
      const float re8[8] = {pr0.x,pr0.y,pr0.z,pr0.w, pr1.x,pr1.y,pr1.z,pr1.w};
      const float im8[8] = {pi0.x,pi0.y,pi0.z,pi0.w, pi1.x,pi1.y,pi1.z,pi1.w};
      bf16x8 vr, vi;
      #pragma unroll
      for (int i = 0; i < 8; ++i){
        const float rv = re8[i] - ((c == kb + i) ? 1.0f : 0.0f);
        vr[i] = (short)f2bf(rv);
        vi[i] = (short)f2bf(im8[i]);
      }
      bhr[ct][kt] = vr; bhi[ct][kt] = vi;
    }
  }

  // ---- load state f32 (D-frag layout) + single bf16 LDS snapshot ----
  float sre[4][2][4], simg[4][2][4];
  #pragma unroll
  for (int rt = 0; rt < 4; ++rt)
    #pragma unroll
    for (int ct = 0; ct < 2; ++ct)
      #pragma unroll
      for (int j = 0; j < 4; ++j){
        const int row = brow + rt*16 + lq*4 + j;
        const int col = cbase + ct*16 + lr;
        const float xr = psi_re[row*DIM + col];
        const float xi = psi_im[row*DIM + col];
        sre [rt][ct][j] = xr;
        simg[rt][ct][j] = xi;
        a_re[rt*16 + lq*4 + j][col] = f2bf(xr);
        a_im[rt*16 + lq*4 + j][col] = f2bf(xi);
      }
  __syncthreads();

  // ---- g = q @ R^T (complex), out = q + g; row-norm partials ----
  #pragma unroll
  for (int rt = 0; rt < 4; ++rt){
    f32x4 ar0 = {0.f,0.f,0.f,0.f}, ar1 = {0.f,0.f,0.f,0.f};
    f32x4 ai0 = {0.f,0.f,0.f,0.f}, ai1 = {0.f,0.f,0.f,0.f};
    #pragma unroll
    for (int kt = 0; kt < 8; ++kt){
      const int arow = rt*16 + lr;          // A-frag: row = lane&15
      const int kofs = kt*32 + lq*8;        //         k   = (lane>>4)*8 + i
      bf16x8 apr = *reinterpret_cast<const bf16x8*>(&a_re[arow][kofs]);
      bf16x8 api = *reinterpret_cast<const bf16x8*>(&a_im[arow][kofs]);
      i32x4 tneg = __builtin_bit_cast(i32x4, api) ^ (i32x4)(int)0x80008000;
      bf16x8 apin = __builtin_bit_cast(bf16x8, tneg);   // -qi
      // g_re = qr@Rr - qi@Ri ; g_im = qr@Ri + qi@Rr
      ar0 = __builtin_amdgcn_mfma_f32_16x16x32_bf16(apr,  bhr[0][kt], ar0, 0,0,0);
      ai0 = __builtin_amdgcn_mfma_f32_16x16x32_bf16(apr,  bhi[0][kt], ai0, 0,0,0);
      ar1 = __builtin_amdgcn_mfma_f32_16x16x32_bf16(apr,  bhr[1][kt], ar1, 0,0,0);
      ai1 = __builtin_amdgcn_mfma_f32_16x16x32_bf16(apr,  bhi[1][kt], ai1, 0,0,0);
      ar0 = __builtin_amdgcn_mfma_f32_16x16x32_bf16(apin, bhi[0][kt], ar0, 0,0,0);
      ai0 = __builtin_amdgcn_mfma_f32_16x16x32_bf16(api,  bhr[0][kt], ai0, 0,0,0);
      ar1 = __builtin_amdgcn_mfma_f32_16x16x32_bf16(apin, bhi[1][kt], ar1, 0,0,0);
      ai1 = __builtin_amdgcn_mfma_f32_16x16x32_bf16(api,  bhr[1][kt], ai1, 0,0,0);
    }
    float ss[4];
    #pragma unroll
    for (int j = 0; j < 4; ++j){
      sre [rt][0][j] += ar0[j];
      simg[rt][0][j] += ai0[j];
      sre [rt][1][j] += ar1[j];
      simg[rt][1][j] += ai1[j];
      float v = sre[rt][0][j]*sre[rt][0][j] + simg[rt][0][j]*simg[rt][0][j]
              + sre[rt][1][j]*sre[rt][1][j] + simg[rt][1][j]*simg[rt][1][j];
      v += __shfl_xor(v, 1);
      v += __shfl_xor(v, 2);
      v += __shfl_xor(v, 4);
      v += __shfl_xor(v, 8);
      ss[j] = v;
    }
    if (lr == 0){
      #pragma unroll
      for (int j = 0; j < 4; ++j)
        partials[rt*16 + lq*4 + j][wv] = ss[j];
    }
  }
  __syncthreads();

  if (tid < 64){
    float acc = 0.f;
    #pragma unroll
    for (int w = 0; w < 8; ++w) acc += partials[tid][w];
    // T==0: reference's scan body never runs -> no normalization
    scales[tid] = (T == 0) ? 1.0f : 1.0f / (sqrtf(acc) + EPSC);
  }
  __syncthreads();

  // ---- scale + store fused ----
  #pragma unroll
  for (int rt = 0; rt < 4; ++rt)
    #pragma unroll
    for (int ct = 0; ct < 2; ++ct)
      #pragma unroll
      for (int j = 0; j < 4; ++j){
        const int row = brow + rt*16 + lq*4 + j;
        const int col = cbase + ct*16 + lr;
        const float sc = scales[rt*16 + lq*4 + j];
        const float xr = sre [rt][ct][j] * sc;
        const float xi = simg[rt][ct][j] * sc;
        if (STORE_COMPLEX){
          out[(size_t)(row*DIM + col)*2 + 0] = xr;
          out[(size_t)(row*DIM + col)*2 + 1] = xi;
        } else {
          out[row*DIM + col] = xr;
        }
      }
}

// ---------------------------------------------------------------------------
// Fallback: the previous verified 10-step kernel (used only if ws too small).
// ---------------------------------------------------------------------------
template<int STORE_COMPLEX>
__global__ __launch_bounds__(512, 2)
void qevolve_kernel(const float* __restrict__ psi_re, const float* __restrict__ psi_im,
                    const float* __restrict__ ham_re, const float* __restrict__ ham_im,
                    const float* __restrict__ hbar,   const int* __restrict__ tsteps,
                    float* __restrict__ out)
{
  __shared__ alignas(16) unsigned short a_re[64][272];
  __shared__ alignas(16) unsigned short a_im[64][272];
  __shared__ float partials[64][8];
  __shared__ float scales[64];

  const int tid  = threadIdx.x;
  const int wv   = tid >> 6;
  const int lane = tid & 63;
  const int lq   = lane >> 4;
  const int lr   = lane & 15;
  const int brow = blockIdx.x << 6;
  const int cbase = wv << 5;
  const float cs = DTC / hbar[0];
  const int T = tsteps[0];

  bf16x8 bhr[2][8], bhi[2][8];
  #pragma unroll
  for (int ct = 0; ct < 2; ++ct){
    const int c = cbase + ct*16 + lr;
    #pragma unroll
    for (int kt = 0; kt < 8; ++kt){
      const int kb = kt*32 + lq*8;
      bf16x8 vr, vi;
      #pragma unroll
      for (int i = 0; i < 8; ++i){
        vr[i] = (short)f2bf(ham_re[c*DIM + kb + i]);
        vi[i] = (short)f2bf(ham_im[c*DIM + kb + i]);
      }
      bhr[ct][kt] = vr; bhi[ct][kt] = vi;
    }
  }

  float sre[4][2][4], simg[4][2][4];
  #pragma unroll
  for (int rt = 0; rt < 4; ++rt)
    #pragma unroll
    for (int ct = 0; ct < 2; ++ct)
      #pragma unroll
      for (int j = 0; j < 4; ++j){
        const int row = brow + rt*16 + lq*4 + j;
        const int col = cbase + ct*16 + lr;
        sre [rt][ct][j] = psi_re[row*DIM + col];
        simg[rt][ct][j] = psi_im[row*DIM + col];
      }

  for (int s = 0; s < T; ++s){
    #pragma unroll
    for (int rt = 0; rt < 4; ++rt)
      #pragma unroll
      for (int ct = 0; ct < 2; ++ct)
        #pragma unroll
        for (int j = 0; j < 4; ++j){
          const int row = rt*16 + lq*4 + j;
          const int col = cbase + ct*16 + lr;
          a_re[row][col] = f2bf(sre [rt][ct][j]);
          a_im[row][col] = f2bf(simg[rt][ct][j]);
        }
    __syncthreads();

    #pragma unroll
    for (int rt = 0; rt < 4; ++rt){
      f32x4 ar0 = {0.f,0.f,0.f,0.f}, ar1 = {0.f,0.f,0.f,0.f};
      f32x4 ai0 = {0.f,0.f,0.f,0.f}, ai1 = {0.f,0.f,0.f,0.f};
      #pragma unroll
      for (int kt = 0; kt < 8; ++kt){
        const int arow = rt*16 + lr;
        const int kofs = kt*32 + lq*8;
        bf16x8 apr = *reinterpret_cast<const bf16x8*>(&a_re[arow][kofs]);
        bf16x8 api = *reinterpret_cast<const bf16x8*>(&a_im[arow][kofs]);
        i32x4 tneg = __builtin_bit_cast(i32x4, api) ^ (i32x4)(int)0x80008000;
        bf16x8 apin = __builtin_bit_cast(bf16x8, tneg);
        ar0 = __builtin_amdgcn_mfma_f32_16x16x32_bf16(apr,  bhr[0][kt], ar0, 0,0,0);
        ai0 = __builtin_amdgcn_mfma_f32_16x16x32_bf16(apr,  bhi[0][kt], ai0, 0,0,0);
        ar1 = __builtin_amdgcn_mfma_f32_16x16x32_bf16(apr,  bhr[1][kt], ar1, 0,0,0);
        ai1 = __builtin_amdgcn_mfma_f32_16x16x32_bf16(apr,  bhi[1][kt], ai1, 0,0,0);
        ar0 = __builtin_amdgcn_mfma_f32_16x16x32_bf16(apin, bhi[0][kt], ar0, 0,0,0);
        ai0 = __builtin_amdgcn_mfma_f32_16x16x32_bf16(api,  bhr[0][kt], ai0, 0,0,0);
        ar1 = __builtin_amdgcn_mfma_f32_16x16x32_bf16(apin, bhi[1][kt], ar1, 0,0,0);
        ai1 = __builtin_amdgcn_mfma_f32_16x16x32_bf16(api,  bhr[1][kt], ai1, 0,0,0);
      }
      float ss[4];
      #pragma unroll
      for (int j = 0; j < 4; ++j){
        sre [rt][0][j] += cs * ai0[j];
        simg[rt][0][j] -= cs * ar0[j];
        sre [rt][1][j] += cs * ai1[j];
        simg[rt][1][j] -= cs * ar1[j];
        float v = sre[rt][0][j]*sre[rt][0][j] + simg[rt][0][j]*simg[rt][0][j]
                + sre[rt][1][j]*sre[rt][1][j] + simg[rt][1][j]*simg[rt][1][j];
        v += __shfl_xor(v, 1);
        v += __shfl_xor(v, 2);
        v += __shfl_xor(v, 4);
        v += __shfl_xor(v, 8);
        ss[j] = v;
      }
      if (lr == 0){
        #pragma unroll
        for (int j = 0; j < 4; ++j)
          partials[rt*16 + lq*4 + j][wv] = ss[j];
      }
    }
    __syncthreads();

    if (tid < 64){
      float acc = 0.f;
      #pragma unroll
      for (int w = 0; w < 8; ++w) acc += partials[tid][w];
      scales[tid] = 1.0f / (sqrtf(acc) + EPSC);
    }
    __syncthreads();

    #pragma unroll
    for (int rt = 0; rt < 4; ++rt)
      #pragma unroll
      for (int j = 0; j < 4; ++j){
        const float sc = scales[rt*16 + lq*4 + j];
        sre [rt][0][j] *= sc; sre [rt][1][j] *= sc;
        simg[rt][0][j] *= sc; simg[rt][1][j] *= sc;
      }
  }

  #pragma unroll
  for (int rt = 0; rt < 4; ++rt)
    #pragma unroll
    for (int ct = 0; ct < 2; ++ct)
      #pragma unroll
      for (int j = 0; j < 4; ++j){
        const int row = brow + rt*16 + lq*4 + j;
        const int col = cbase + ct*16 + lr;
        if (STORE_COMPLEX){
          out[(size_t)(row*DIM + col)*2 + 0] = sre [rt][ct][j];
          out[(size_t)(row*DIM + col)*2 + 1] = simg[rt][ct][j];
        } else {
          out[row*DIM + col] = sre[rt][ct][j];
        }
      }
}

extern "C" void kernel_launch(void* const* d_in, const int* in_sizes, int n_in,
                              void* d_out, int out_size, void* d_ws, size_t ws_size,
                              hipStream_t stream)
{
  const float* psi_re = (const float*)d_in[0];
  const float* psi_im = (const float*)d_in[1];
  const float* ham_re = (const float*)d_in[2];
  const float* ham_im = (const float*)d_in[3];
  const float* hbar   = (const float*)d_in[4];
  const int*   tstep  = (const int*)d_in[5];
  float* out = (float*)d_out;

  const size_t NMAT = (size_t)DIM * DIM;            // 65536
  const size_t WS_NEED = 6 * NMAT * sizeof(float);  // 1.5 MB

  dim3 grid(SEQ / 64), block(512);

  if (d_ws != nullptr && ws_size >= WS_NEED){
    float* w   = (float*)d_ws;
    float* m1r = w + 0*NMAT; float* m1i = w + 1*NMAT;
    float* Ar  = w + 2*NMAT; float* Ai  = w + 3*NMAT;
    float* Br  = w + 4*NMAT; float* Bi  = w + 5*NMAT;

    // P = (I + cH)^T_power via square-and-multiply, 5 bits (T <= 31).
    k_init   <<<256, 256, 0, stream>>>(ham_re, ham_im, hbar, m1r, m1i, Ar, Ai);
    k_step<4><<<256, 256, 0, stream>>>(Ar, Ai, m1r, m1i, tstep, Br, Bi);
    k_step<3><<<256, 256, 0, stream>>>(Br, Bi, m1r, m1i, tstep, Ar, Ai);
    k_step<2><<<256, 256, 0, stream>>>(Ar, Ai, m1r, m1i, tstep, Br, Bi);
    k_step<1><<<256, 256, 0, stream>>>(Br, Bi, m1r, m1i, tstep, Ar, Ai);
    k_step<0><<<256, 256, 0, stream>>>(Ar, Ai, m1r, m1i, tstep, Br, Bi);
    // result in (Br, Bi)

    if (out_size == 2 * SEQ * DIM)
      apply_kernel<1><<<grid, block, 0, stream>>>(psi_re, psi_im, Br, Bi, tstep, out);
    else
      apply_kernel<0><<<grid, block, 0, stream>>>(psi_re, psi_im, Br, Bi, tstep, out);
  } else {
    // Fallback: previous verified 10-step kernel.
    if (out_size == 2 * SEQ * DIM)
      qevolve_kernel<1><<<grid, block, 0, stream>>>(psi_re, psi_im, ham_re, ham_im, hbar, tstep, out);
    else
      qevolve_kernel<0><<<grid, block, 0, stream>>>(psi_re, psi_im, ham_re, ham_im, hbar, tstep, out);
  }

  (void)in_sizes; (void)n_in;
}

// Round 2
// 274.775 us; speedup vs baseline: 3.3626x; 2.0663x over previous
//
#include <hip/hip_runtime.h>

#define SEQ 131072
#define DIM 256
#define DTC 0.1f
#define EPSC 1e-8f

typedef __attribute__((ext_vector_type(8))) short bf16x8;
typedef __attribute__((ext_vector_type(4))) float f32x4;
typedef __attribute__((ext_vector_type(4))) int   i32x4;

// f32 -> bf16 round-to-nearest-even (no NaN handling needed: data is bounded)
static __device__ __forceinline__ unsigned short f2bf(float f){
  unsigned int u = __builtin_bit_cast(unsigned int, f);
  u += 0x7fffu + ((u >> 16) & 1u);
  return (unsigned short)(u >> 16);
}

// ---------------------------------------------------------------------------
// Stage 0: M1 = I + cH  (c = -i*dt/hbar), and P = I.   65536 threads.
//   cH = -i*s*(Hr + i*Hi) = s*Hi - i*s*Hr   with s = dt/hbar.
// ---------------------------------------------------------------------------
__global__ __launch_bounds__(256)
void k_init(const float* __restrict__ hr, const float* __restrict__ hi,
            const float* __restrict__ hbar,
            float* __restrict__ m1r, float* __restrict__ m1i,
            float* __restrict__ pr,  float* __restrict__ pi)
{
  const int idx = blockIdx.x * 256 + threadIdx.x;   // grid 256 -> 65536
  const int r = idx >> 8, c = idx & 255;
  const float s = DTC / hbar[0];
  const float diag = (r == c) ? 1.0f : 0.0f;
  m1r[idx] = diag + s * hi[idx];
  m1i[idx] =       -s * hr[idx];
  pr [idx] = diag;
  pi [idx] = 0.0f;
}

// ---------------------------------------------------------------------------
// One square-and-multiply stage:  out = (in*in) * (bit(T,BIT) ? M1 : I)
// Block r computes output row r. Both matmuls fused via LDS row buffer.
// ---------------------------------------------------------------------------
template<int BIT>
__global__ __launch_bounds__(256)
void k_step(const float* __restrict__ inr, const float* __restrict__ ini,
            const float* __restrict__ m1r, const float* __restrict__ m1i,
            const int* __restrict__ ts,
            float* __restrict__ outr, float* __restrict__ outi)
{
  __shared__ float rr[256], ri[256], sr[256], si[256];
  const int r = blockIdx.x, c = threadIdx.x;
  rr[c] = inr[r*256 + c];
  ri[c] = ini[r*256 + c];
  __syncthreads();

  float ar = 0.f, ai = 0.f;
  for (int k = 0; k < 256; ++k){
    const float br = inr[k*256 + c], bi = ini[k*256 + c];  // coalesced across c
    const float xr = rr[k],          xi = ri[k];           // LDS broadcast
    ar = fmaf(xr, br, fmaf(-xi, bi, ar));
    ai = fmaf(xr, bi, fmaf( xi, br, ai));
  }

  const bool bit = ((ts[0] >> BIT) & 1) != 0;   // block-uniform branch
  if (!bit){
    outr[r*256 + c] = ar; outi[r*256 + c] = ai;
    return;
  }
  sr[c] = ar; si[c] = ai;
  __syncthreads();
  float orr = 0.f, oii = 0.f;
  for (int k = 0; k < 256; ++k){
    const float br = m1r[k*256 + c], bi = m1i[k*256 + c];
    const float xr = sr[k],          xi = si[k];
    orr = fmaf(xr, br, fmaf(-xi, bi, orr));
    oii = fmaf(xr, bi, fmaf( xi, br, oii));
  }
  outr[r*256 + c] = orr; outi[r*256 + c] = oii;
}

// ---------------------------------------------------------------------------
// Fragment precompute: build bf16 B-fragments of R = P - I ONCE, in the exact
// per-thread layout apply_kernel consumes:  frag[((ct*8+kt)*2+p)*512 + tid]
// (bf16x8 elements, 16 B).  8192 threads; P-row reads fully coalesced.
//   thread n: c = n>>5 (P row), kb8 = (n&31)*8 (8 consecutive k's)
//   -> kt = kb8>>5, lq = (kb8>>3)&3, wv = c>>5, ct = (c>>4)&1, lr = c&15
//   -> tid = wv*64 + lq*16 + lr
// ---------------------------------------------------------------------------
__global__ __launch_bounds__(512)
void k_frag(const float* __restrict__ Pre, const float* __restrict__ Pim,
            unsigned short* __restrict__ fragbuf)
{
  const int n   = blockIdx.x * 512 + threadIdx.x;   // grid 16 -> 8192
  const int c   = n >> 5;
  const int kb8 = (n & 31) * 8;
  const int kt  = kb8 >> 5;
  const int lq  = (kb8 >> 3) & 3;
  const int wv  = c >> 5;
  const int ct  = (c >> 4) & 1;
  const int lr  = c & 15;
  const int tid = wv*64 + lq*16 + lr;

  const float4 pr0 = *reinterpret_cast<const float4*>(&Pre[c*DIM + kb8]);
  const float4 pr1 = *reinterpret_cast<const float4*>(&Pre[c*DIM + kb8 + 4]);
  const float4 pi0 = *reinterpret_cast<const float4*>(&Pim[c*DIM + kb8]);
  const float4 pi1 = *reinterpret_cast<const float4*>(&Pim[c*DIM + kb8 + 4]);
  const float re8[8] = {pr0.x,pr0.y,pr0.z,pr0.w, pr1.x,pr1.y,pr1.z,pr1.w};
  const float im8[8] = {pi0.x,pi0.y,pi0.z,pi0.w, pi1.x,pi1.y,pi1.z,pi1.w};

  bf16x8 vr, vi;
  #pragma unroll
  for (int i = 0; i < 8; ++i){
    const float rv = re8[i] - ((c == kb8 + i) ? 1.0f : 0.0f);   // R = P - I
    vr[i] = (short)f2bf(rv);
    vi[i] = (short)f2bf(im8[i]);
  }
  bf16x8* fb = reinterpret_cast<bf16x8*>(fragbuf);
  fb[((ct*8 + kt)*2 + 0)*512 + tid] = vr;
  fb[((ct*8 + kt)*2 + 1)*512 + tid] = vi;
}

// ---------------------------------------------------------------------------
// Main apply:  out = normalize_rows( q0 + q0 @ R^T ),  R = M^T_power - I.
// USE_FRAG: B-fragments come pre-converted & laid out from ws (coalesced);
// else computed inline from Pre/Pim (fallback when ws is small).
// ---------------------------------------------------------------------------
template<int STORE_COMPLEX, int USE_FRAG>
__global__ __launch_bounds__(512, 2)
void apply_kernel(const float* __restrict__ psi_re, const float* __restrict__ psi_im,
                  const float* __restrict__ Pre,    const float* __restrict__ Pim,
                  const unsigned short* __restrict__ fragbuf,
                  const int* __restrict__ tsteps,   float* __restrict__ out)
{
  __shared__ alignas(16) unsigned short a_re[64][272];
  __shared__ alignas(16) unsigned short a_im[64][272];
  __shared__ float partials[64][8];
  __shared__ float scales[64];

  const int tid  = threadIdx.x;
  const int wv   = tid >> 6;
  const int lane = tid & 63;
  const int lq   = lane >> 4;   // 16-lane group
  const int lr   = lane & 15;
  const int brow = blockIdx.x << 6;
  const int cbase = wv << 5;    // wave's first column
  const int T = tsteps[0];

  // ---- B fragments: B[k][c] = R[c][k], bf16 ----
  bf16x8 bhr[2][8], bhi[2][8];
  if constexpr (USE_FRAG){
    const bf16x8* fb = reinterpret_cast<const bf16x8*>(fragbuf);
    #pragma unroll
    for (int ct = 0; ct < 2; ++ct)
      #pragma unroll
      for (int kt = 0; kt < 8; ++kt){
        bhr[ct][kt] = fb[((ct*8 + kt)*2 + 0)*512 + tid];   // 1 KB/wave-inst
        bhi[ct][kt] = fb[((ct*8 + kt)*2 + 1)*512 + tid];
      }
  } else {
    #pragma unroll
    for (int ct = 0; ct < 2; ++ct){
      const int c = cbase + ct*16 + lr;
      #pragma unroll
      for (int kt = 0; kt < 8; ++kt){
        const int kb = kt*32 + lq*8;
        const float4 pr0 = *reinterpret_cast<const float4*>(&Pre[c*DIM + kb]);
        const float4 pr1 = *reinterpret_cast<const float4*>(&Pre[c*DIM + kb + 4]);
        const float4 pi0 = *reinterpret_cast<const float4*>(&Pim[c*DIM + kb]);
        const float4 pi1 = *reinterpret_cast<const float4*>(&Pim[c*DIM + kb + 4]);
        const float re8[8] = {pr0.x,pr0.y,pr0.z,pr0.w, pr1.x,pr1.y,pr1.z,pr1.w};
        const float im8[8] = {pi0.x,pi0.y,pi0.z,pi0.w, pi1.x,pi1.y,pi1.z,pi1.w};
        bf16x8 vr, vi;
        #pragma unroll
        for (int i = 0; i < 8; ++i){
          const float rv = re8[i] - ((c == kb + i) ? 1.0f : 0.0f);
          vr[i] = (short)f2bf(rv);
          vi[i] = (short)f2bf(im8[i]);
        }
        bhr[ct][kt] = vr; bhi[ct][kt] = vi;
      }
    }
  }

  // ---- load state f32 (D-frag layout) + single bf16 LDS snapshot ----
  float sre[4][2][4], simg[4][2][4];
  #pragma unroll
  for (int rt = 0; rt < 4; ++rt)
    #pragma unroll
    for (int ct = 0; ct < 2; ++ct)
      #pragma unroll
      for (int j = 0; j < 4; ++j){
        const int row = brow + rt*16 + lq*4 + j;
        const int col = cbase + ct*16 + lr;
        const float xr = psi_re[row*DIM + col];
        const float xi = psi_im[row*DIM + col];
        sre [rt][ct][j] = xr;
        simg[rt][ct][j] = xi;
        a_re[rt*16 + lq*4 + j][col] = f2bf(xr);
        a_im[rt*16 + lq*4 + j][col] = f2bf(xi);
      }
  __syncthreads();

  // ---- g = q @ R^T (complex), out = q + g; row-norm partials ----
  #pragma unroll
  for (int rt = 0; rt < 4; ++rt){
    f32x4 ar0 = {0.f,0.f,0.f,0.f}, ar1 = {0.f,0.f,0.f,0.f};
    f32x4 ai0 = {0.f,0.f,0.f,0.f}, ai1 = {0.f,0.f,0.f,0.f};
    #pragma unroll
    for (int kt = 0; kt < 8; ++kt){
      const int arow = rt*16 + lr;          // A-frag: row = lane&15
      const int kofs = kt*32 + lq*8;        //         k   = (lane>>4)*8 + i
      bf16x8 apr = *reinterpret_cast<const bf16x8*>(&a_re[arow][kofs]);
      bf16x8 api = *reinterpret_cast<const bf16x8*>(&a_im[arow][kofs]);
      i32x4 tneg = __builtin_bit_cast(i32x4, api) ^ (i32x4)(int)0x80008000;
      bf16x8 apin = __builtin_bit_cast(bf16x8, tneg);   // -qi
      // g_re = qr@Rr - qi@Ri ; g_im = qr@Ri + qi@Rr
      ar0 = __builtin_amdgcn_mfma_f32_16x16x32_bf16(apr,  bhr[0][kt], ar0, 0,0,0);
      ai0 = __builtin_amdgcn_mfma_f32_16x16x32_bf16(apr,  bhi[0][kt], ai0, 0,0,0);
      ar1 = __builtin_amdgcn_mfma_f32_16x16x32_bf16(apr,  bhr[1][kt], ar1, 0,0,0);
      ai1 = __builtin_amdgcn_mfma_f32_16x16x32_bf16(apr,  bhi[1][kt], ai1, 0,0,0);
      ar0 = __builtin_amdgcn_mfma_f32_16x16x32_bf16(apin, bhi[0][kt], ar0, 0,0,0);
      ai0 = __builtin_amdgcn_mfma_f32_16x16x32_bf16(api,  bhr[0][kt], ai0, 0,0,0);
      ar1 = __builtin_amdgcn_mfma_f32_16x16x32_bf16(apin, bhi[1][kt], ar1, 0,0,0);
      ai1 = __builtin_amdgcn_mfma_f32_16x16x32_bf16(api,  bhr[1][kt], ai1, 0,0,0);
    }
    float ss[4];
    #pragma unroll
    for (int j = 0; j < 4; ++j){
      sre [rt][0][j] += ar0[j];
      simg[rt][0][j] += ai0[j];
      sre [rt][1][j] += ar1[j];
      simg[rt][1][j] += ai1[j];
      float v = sre[rt][0][j]*sre[rt][0][j] + simg[rt][0][j]*simg[rt][0][j]
              + sre[rt][1][j]*sre[rt][1][j] + simg[rt][1][j]*simg[rt][1][j];
      v += __shfl_xor(v, 1);
      v += __shfl_xor(v, 2);
      v += __shfl_xor(v, 4);
      v += __shfl_xor(v, 8);
      ss[j] = v;
    }
    if (lr == 0){
      #pragma unroll
      for (int j = 0; j < 4; ++j)
        partials[rt*16 + lq*4 + j][wv] = ss[j];
    }
  }
  __syncthreads();

  if (tid < 64){
    float acc = 0.f;
    #pragma unroll
    for (int w = 0; w < 8; ++w) acc += partials[tid][w];
    // T==0: reference's scan body never runs -> no normalization
    scales[tid] = (T == 0) ? 1.0f : 1.0f / (sqrtf(acc) + EPSC);
  }
  __syncthreads();

  // ---- scale + store fused ----
  #pragma unroll
  for (int rt = 0; rt < 4; ++rt)
    #pragma unroll
    for (int ct = 0; ct < 2; ++ct)
      #pragma unroll
      for (int j = 0; j < 4; ++j){
        const int row = brow + rt*16 + lq*4 + j;
        const int col = cbase + ct*16 + lr;
        const float sc = scales[rt*16 + lq*4 + j];
        const float xr = sre [rt][ct][j] * sc;
        const float xi = simg[rt][ct][j] * sc;
        if (STORE_COMPLEX){
          float2 v2 = {xr, xi};
          *reinterpret_cast<float2*>(&out[(size_t)(row*DIM + col)*2]) = v2;
        } else {
          out[row*DIM + col] = xr;
        }
      }
}

// ---------------------------------------------------------------------------
// Fallback: the original verified 10-step kernel (used only if ws too small).
// ---------------------------------------------------------------------------
template<int STORE_COMPLEX>
__global__ __launch_bounds__(512, 2)
void qevolve_kernel(const float* __restrict__ psi_re, const float* __restrict__ psi_im,
                    const float* __restrict__ ham_re, const float* __restrict__ ham_im,
                    const float* __restrict__ hbar,   const int* __restrict__ tsteps,
                    float* __restrict__ out)
{
  __shared__ alignas(16) unsigned short a_re[64][272];
  __shared__ alignas(16) unsigned short a_im[64][272];
  __shared__ float partials[64][8];
  __shared__ float scales[64];

  const int tid  = threadIdx.x;
  const int wv   = tid >> 6;
  const int lane = tid & 63;
  const int lq   = lane >> 4;
  const int lr   = lane & 15;
  const int brow = blockIdx.x << 6;
  const int cbase = wv << 5;
  const float cs = DTC / hbar[0];
  const int T = tsteps[0];

  bf16x8 bhr[2][8], bhi[2][8];
  #pragma unroll
  for (int ct = 0; ct < 2; ++ct){
    const int c = cbase + ct*16 + lr;
    #pragma unroll
    for (int kt = 0; kt < 8; ++kt){
      const int kb = kt*32 + lq*8;
      bf16x8 vr, vi;
      #pragma unroll
      for (int i = 0; i < 8; ++i){
        vr[i] = (short)f2bf(ham_re[c*DIM + kb + i]);
        vi[i] = (short)f2bf(ham_im[c*DIM + kb + i]);
      }
      bhr[ct][kt] = vr; bhi[ct][kt] = vi;
    }
  }

  float sre[4][2][4], simg[4][2][4];
  #pragma unroll
  for (int rt = 0; rt < 4; ++rt)
    #pragma unroll
    for (int ct = 0; ct < 2; ++ct)
      #pragma unroll
      for (int j = 0; j < 4; ++j){
        const int row = brow + rt*16 + lq*4 + j;
        const int col = cbase + ct*16 + lr;
        sre [rt][ct][j] = psi_re[row*DIM + col];
        simg[rt][ct][j] = psi_im[row*DIM + col];
      }

  for (int s = 0; s < T; ++s){
    #pragma unroll
    for (int rt = 0; rt < 4; ++rt)
      #pragma unroll
      for (int ct = 0; ct < 2; ++ct)
        #pragma unroll
        for (int j = 0; j < 4; ++j){
          const int row = rt*16 + lq*4 + j;
          const int col = cbase + ct*16 + lr;
          a_re[row][col] = f2bf(sre [rt][ct][j]);
          a_im[row][col] = f2bf(simg[rt][ct][j]);
        }
    __syncthreads();

    #pragma unroll
    for (int rt = 0; rt < 4; ++rt){
      f32x4 ar0 = {0.f,0.f,0.f,0.f}, ar1 = {0.f,0.f,0.f,0.f};
      f32x4 ai0 = {0.f,0.f,0.f,0.f}, ai1 = {0.f,0.f,0.f,0.f};
      #pragma unroll
      for (int kt = 0; kt < 8; ++kt){
        const int arow = rt*16 + lr;
        const int kofs = kt*32 + lq*8;
        bf16x8 apr = *reinterpret_cast<const bf16x8*>(&a_re[arow][kofs]);
        bf16x8 api = *reinterpret_cast<const bf16x8*>(&a_im[arow][kofs]);
        i32x4 tneg = __builtin_bit_cast(i32x4, api) ^ (i32x4)(int)0x80008000;
        bf16x8 apin = __builtin_bit_cast(bf16x8, tneg);
        ar0 = __builtin_amdgcn_mfma_f32_16x16x32_bf16(apr,  bhr[0][kt], ar0, 0,0,0);
        ai0 = __builtin_amdgcn_mfma_f32_16x16x32_bf16(apr,  bhi[0][kt], ai0, 0,0,0);
        ar1 = __builtin_amdgcn_mfma_f32_16x16x32_bf16(apr,  bhr[1][kt], ar1, 0,0,0);
        ai1 = __builtin_amdgcn_mfma_f32_16x16x32_bf16(apr,  bhi[1][kt], ai1, 0,0,0);
        ar0 = __builtin_amdgcn_mfma_f32_16x16x32_bf16(apin, bhi[0][kt], ar0, 0,0,0);
        ai0 = __builtin_amdgcn_mfma_f32_16x16x32_bf16(api,  bhr[0][kt], ai0, 0,0,0);
        ar1 = __builtin_amdgcn_mfma_f32_16x16x32_bf16(apin, bhi[1][kt], ar1, 0,0,0);
        ai1 = __builtin_amdgcn_mfma_f32_16x16x32_bf16(api,  bhr[1][kt], ai1, 0,0,0);
      }
      float ss[4];
      #pragma unroll
      for (int j = 0; j < 4; ++j){
        sre [rt][0][j] += cs * ai0[j];
        simg[rt][0][j] -= cs * ar0[j];
        sre [rt][1][j] += cs * ai1[j];
        simg[rt][1][j] -= cs * ar1[j];
        float v = sre[rt][0][j]*sre[rt][0][j] + simg[rt][0][j]*simg[rt][0][j]
                + sre[rt][1][j]*sre[rt][1][j] + simg[rt][1][j]*simg[rt][1][j];
        v += __shfl_xor(v, 1);
        v += __shfl_xor(v, 2);
        v += __shfl_xor(v, 4);
        v += __shfl_xor(v, 8);
        ss[j] = v;
      }
      if (lr == 0){
        #pragma unroll
        for (int j = 0; j < 4; ++j)
          partials[rt*16 + lq*4 + j][wv] = ss[j];
      }
    }
    __syncthreads();

    if (tid < 64){
      float acc = 0.f;
      #pragma unroll
      for (int w = 0; w < 8; ++w) acc += partials[tid][w];
      scales[tid] = 1.0f / (sqrtf(acc) + EPSC);
    }
    __syncthreads();

    #pragma unroll
    for (int rt = 0; rt < 4; ++rt)
      #pragma unroll
      for (int j = 0; j < 4; ++j){
        const float sc = scales[rt*16 + lq*4 + j];
        sre [rt][0][j] *= sc; sre [rt][1][j] *= sc;
        simg[rt][0][j] *= sc; simg[rt][1][j] *= sc;
      }
  }

  #pragma unroll
  for (int rt = 0; rt < 4; ++rt)
    #pragma unroll
    for (int ct = 0; ct < 2; ++ct)
      #pragma unroll
      for (int j = 0; j < 4; ++j){
        const int row = brow + rt*16 + lq*4 + j;
        const int col = cbase + ct*16 + lr;
        if (STORE_COMPLEX){
          out[(size_t)(row*DIM + col)*2 + 0] = sre [rt][ct][j];
          out[(size_t)(row*DIM + col)*2 + 1] = simg[rt][ct][j];
        } else {
          out[row*DIM + col] = sre[rt][ct][j];
        }
      }
}

extern "C" void kernel_launch(void* const* d_in, const int* in_sizes, int n_in,
                              void* d_out, int out_size, void* d_ws, size_t ws_size,
                              hipStream_t stream)
{
  const float* psi_re = (const float*)d_in[0];
  const float* psi_im = (const float*)d_in[1];
  const float* ham_re = (const float*)d_in[2];
  const float* ham_im = (const float*)d_in[3];
  const float* hbar   = (const float*)d_in[4];
  const int*   tstep  = (const int*)d_in[5];
  float* out = (float*)d_out;

  const size_t NMAT    = (size_t)DIM * DIM;             // 65536
  const size_t WS_MAT  = 6 * NMAT * sizeof(float);      // 1.5 MB
  const size_t WS_FRAG = 2 * 8 * 2 * 512 * 16;          // 256 KB (bf16x8 frags)

  dim3 grid(SEQ / 64), block(512);
  const bool cplx = (out_size == 2 * SEQ * DIM);

  if (d_ws != nullptr && ws_size >= WS_MAT){
    float* w   = (float*)d_ws;
    float* m1r = w + 0*NMAT; float* m1i = w + 1*NMAT;
    float* Ar  = w + 2*NMAT; float* Ai  = w + 3*NMAT;
    float* Br  = w + 4*NMAT; float* Bi  = w + 5*NMAT;
    unsigned short* fragbuf = (unsigned short*)(w + 6*NMAT);  // 16B-aligned

    // P = (I + cH)^T_power via square-and-multiply, 5 bits (T <= 31).
    k_init   <<<256, 256, 0, stream>>>(ham_re, ham_im, hbar, m1r, m1i, Ar, Ai);
    k_step<4><<<256, 256, 0, stream>>>(Ar, Ai, m1r, m1i, tstep, Br, Bi);
    k_step<3><<<256, 256, 0, stream>>>(Br, Bi, m1r, m1i, tstep, Ar, Ai);
    k_step<2><<<256, 256, 0, stream>>>(Ar, Ai, m1r, m1i, tstep, Br, Bi);
    k_step<1><<<256, 256, 0, stream>>>(Br, Bi, m1r, m1i, tstep, Ar, Ai);
    k_step<0><<<256, 256, 0, stream>>>(Ar, Ai, m1r, m1i, tstep, Br, Bi);
    // result P in (Br, Bi)

    if (ws_size >= WS_MAT + WS_FRAG){
      k_frag<<<16, 512, 0, stream>>>(Br, Bi, fragbuf);   // R = P - I, frag layout
      if (cplx)
        apply_kernel<1,1><<<grid, block, 0, stream>>>(psi_re, psi_im, Br, Bi, fragbuf, tstep, out);
      else
        apply_kernel<0,1><<<grid, block, 0, stream>>>(psi_re, psi_im, Br, Bi, fragbuf, tstep, out);
    } else {
      if (cplx)
        apply_kernel<1,0><<<grid, block, 0, stream>>>(psi_re, psi_im, Br, Bi, nullptr, tstep, out);
      else
        apply_kernel<0,0><<<grid, block, 0, stream>>>(psi_re, psi_im, Br, Bi, nullptr, tstep, out);
    }
  } else {
    // Fallback: original verified 10-step kernel.
    if (cplx)
      qevolve_kernel<1><<<grid, block, 0, stream>>>(psi_re, psi_im, ham_re, ham_im, hbar, tstep, out);
    else
      qevolve_kernel<0><<<grid, block, 0, stream>>>(psi_re, psi_im, ham_re, ham_im, hbar, tstep, out);
  }

  (void)in_sizes; (void)n_in;
}